// Round 8
// baseline (429.589 us; speedup 1.0000x reference)
//
#include <hip/hip_runtime.h>
#include <hip/hip_bf16.h>

// Problem constants
#define Bc   4
#define Tc   1024
#define Cc   768
#define Hc   12
#define HSc  64
#define VDc  128
#define NQKV 4608   // gemm N for qkv (4*768 Q/K + 1536 V)
#define YLD  3072   // Y row stride: Q/K only (V goes to Vt)
#define NROWS 4096  // B*T
#define HVD  1536   // H*VD

// Y (qk) column offsets
#define Q1OFF 0
#define K1OFF 768
#define Q2OFF 1536
#define K2OFF 2304

typedef __bf16 bf16x8 __attribute__((ext_vector_type(8)));
typedef float f32x4 __attribute__((ext_vector_type(4)));

#define PW_S 36   // P row stride in dwords: 144B rows, 16B aligned, <=2-way banks
// exp(s*0.125) == exp2(s * 0.125*log2(e))
#define EXP2SCALE 0.18033688011112042f

static __device__ __forceinline__ float bf2f(unsigned short s) {
    return __uint_as_float(((unsigned int)s) << 16);
}
static __device__ __forceinline__ unsigned short f2bf(float f) {
    unsigned int u = __float_as_uint(f);
    unsigned int r = (u + 0x7FFFu + ((u >> 16) & 1u)) >> 16;  // round-nearest-even
    return (unsigned short)r;
}
static __device__ __forceinline__ unsigned int pack2bf(float lo, float hi) {
    // bf16(lo) | bf16(hi)<<16, half-up rounding (values >= 0)
    unsigned int a = (__float_as_uint(lo) + 0x8000u) >> 16;
    unsigned int b = (__float_as_uint(hi) + 0x8000u) & 0xFFFF0000u;
    return a | b;
}

// async global->LDS 16B per lane; lds base must be wave-uniform
static __device__ __forceinline__ void load16_lds(const void* g, void* l) {
    __builtin_amdgcn_global_load_lds(
        (const __attribute__((address_space(1))) void*)g,
        (__attribute__((address_space(3))) void*)l, 16, 0, 0);
}

// ---------------------------------------------------------------------------
// cast fp32 -> bf16, 4 elts/thread
// ---------------------------------------------------------------------------
__global__ __launch_bounds__(256) void cast_bf16(
    const float* __restrict__ src, unsigned short* __restrict__ dst)
{
    int i = blockIdx.x * 256 + threadIdx.x;
    float4 v = *(const float4*)(src + (size_t)i * 4);
    ushort4 u;
    u.x = f2bf(v.x); u.y = f2bf(v.y); u.z = f2bf(v.z); u.w = f2bf(v.w);
    *(ushort4*)(dst + (size_t)i * 4) = u;
}

// ---------------------------------------------------------------------------
// Transpose-repack the 5 projection weights into WcatT[n][k] bf16, k-contig.
// ---------------------------------------------------------------------------
__global__ __launch_bounds__(256) void trans_w(
    const float* __restrict__ Wq1, const float* __restrict__ Wk1,
    const float* __restrict__ Wq2, const float* __restrict__ Wk2,
    const float* __restrict__ Wv, unsigned short* __restrict__ WcatT)
{
    __shared__ float tile[64][65];
    int tid = threadIdx.x;
    int t = blockIdx.x;
    int kt = t % 12, nt = t / 12;
    int k0 = kt * 64, n0 = nt * 64;
    const float* src;
    int stride;
    if (n0 < 3072) {
        int which = n0 / 768, m = n0 - which * 768, h = m >> 6;
        const float* W = (which == 0) ? Wq1 : (which == 1) ? Wk1 : (which == 2) ? Wq2 : Wk2;
        src = W + ((size_t)h * 768 + k0) * 64;
        stride = 64;
    } else {
        int rel = n0 - 3072, h = rel >> 7, e0 = rel & 127;
        src = Wv + ((size_t)h * 768 + k0) * 128 + e0;
        stride = 128;
    }
    for (int i = tid; i < 4096; i += 256) {
        int kl = i >> 6, dl = i & 63;
        tile[dl][kl] = src[(size_t)kl * stride + dl];
    }
    __syncthreads();
    for (int i = tid; i < 4096; i += 256) {
        int nl = i >> 6, kl = i & 63;
        WcatT[(size_t)(n0 + nl) * 768 + k0 + kl] = f2bf(tile[nl][kl]);
    }
}

// ---------------------------------------------------------------------------
// lambda per head
// ---------------------------------------------------------------------------
__global__ __launch_bounds__(64) void lambda_kernel(
    const float* __restrict__ lq1, const float* __restrict__ lk1,
    const float* __restrict__ lq2, const float* __restrict__ lk2,
    const int* __restrict__ layer_idx, float* __restrict__ lam)
{
    int h = blockIdx.x, l = threadIdx.x;
    float li = (float)layer_idx[0];
    float dyn = 0.8f - 0.6f * expf(-0.3f * (li - 1.0f));
    int i = h * HSc + l;
    float v = expf(lq1[i] * lk1[i]) - expf(lq2[i] * lk2[i]) + dyn;
    #pragma unroll
    for (int off = 32; off; off >>= 1) v += __shfl_xor(v, off);
    if (l == 0) lam[h] = v * (1.0f / 64.0f);
}

// ---------------------------------------------------------------------------
// MFMA GEMM (m97 structure): C[M][LDC] = A[M][KD] * Bt[N][KD]^T, bf16 inputs.
// SPLITV: cols >= 3072 (V projection) -> written transposed to VtOut[bh][e][t].
// ---------------------------------------------------------------------------
template<int TN, int KD, int LDC, bool OUT_BIAS, bool SPLITV>
__global__ __launch_bounds__(256) void gemm_mfma(
    const unsigned short* __restrict__ A, const unsigned short* __restrict__ Bt,
    unsigned short* __restrict__ Cb, float* __restrict__ Cf,
    const float* __restrict__ bias, unsigned short* __restrict__ VtOut)
{
    constexpr int BN = TN * 32;
    constexpr int JB = TN / 2;
    __shared__ unsigned short As[128 * 32];
    __shared__ unsigned short Bs[BN * 32];
    int tid = threadIdx.x, lane = tid & 63, w = tid >> 6;
    int wm = w >> 1, wn = w & 1;
    int m0 = blockIdx.y * 128, n0 = blockIdx.x * BN;

    int lr = lane >> 2, lq = lane & 3;
    const unsigned short* gA[2];
    const unsigned short* gB[JB];
    #pragma unroll
    for (int j = 0; j < 2; ++j) {
        int row = w * 32 + j * 16 + lr;
        int qg = lq ^ ((row >> 1) & 3);
        gA[j] = A + (size_t)(m0 + row) * KD + qg * 8;
    }
    #pragma unroll
    for (int j = 0; j < JB; ++j) {
        int row = w * (JB * 16) + j * 16 + lr;
        int qg = lq ^ ((row >> 1) & 3);
        gB[j] = Bt + (size_t)(n0 + row) * KD + qg * 8;
    }

    int rr = lane & 15, qd = lane >> 4;
    const unsigned short* aAddr[4];
    const unsigned short* bAddr[TN];
    #pragma unroll
    for (int i = 0; i < 4; ++i) {
        int row = wm * 64 + i * 16 + rr;
        int qs = qd ^ ((row >> 1) & 3);
        aAddr[i] = As + row * 32 + qs * 8;
    }
    #pragma unroll
    for (int t = 0; t < TN; ++t) {
        int row = wn * (TN * 16) + t * 16 + rr;
        int qs = qd ^ ((row >> 1) & 3);
        bAddr[t] = Bs + row * 32 + qs * 8;
    }

    f32x4 acc[4][TN];
    #pragma unroll
    for (int i = 0; i < 4; ++i)
        #pragma unroll
        for (int t = 0; t < TN; ++t) acc[i][t] = {0.f, 0.f, 0.f, 0.f};

    for (int k = 0; k < KD / 32; ++k) {
        __syncthreads();
        load16_lds(gA[0], As + (w * 2 + 0) * 512);
        load16_lds(gA[1], As + (w * 2 + 1) * 512);
        #pragma unroll
        for (int j = 0; j < JB; ++j)
            load16_lds(gB[j], Bs + (w * JB + j) * 512);
        gA[0] += 32; gA[1] += 32;
        #pragma unroll
        for (int j = 0; j < JB; ++j) gB[j] += 32;
        __syncthreads();

        bf16x8 af[4], bfr[TN];
        #pragma unroll
        for (int i = 0; i < 4; ++i) af[i] = *(const bf16x8*)aAddr[i];
        #pragma unroll
        for (int t = 0; t < TN; ++t) bfr[t] = *(const bf16x8*)bAddr[t];
        #pragma unroll
        for (int i = 0; i < 4; ++i)
            #pragma unroll
            for (int t = 0; t < TN; ++t)
                acc[i][t] = __builtin_amdgcn_mfma_f32_16x16x32_bf16(af[i], bfr[t], acc[i][t], 0, 0, 0);
    }

    #pragma unroll
    for (int t = 0; t < TN; ++t) {
        int col = n0 + wn * (TN * 16) + t * 16 + rr;
        if (SPLITV && col >= 3072) {
            int rel = col - 3072, hh = rel >> 7, e = rel & 127;
            #pragma unroll
            for (int i = 0; i < 4; ++i) {
                int row0 = m0 + wm * 64 + i * 16 + qd * 4;
                int b = row0 >> 10, tt = row0 & 1023;
                ushort4 pk;
                pk.x = f2bf(acc[i][t][0]); pk.y = f2bf(acc[i][t][1]);
                pk.z = f2bf(acc[i][t][2]); pk.w = f2bf(acc[i][t][3]);
                *(ushort4*)&VtOut[(size_t)((b * Hc + hh) * 128 + e) * 1024 + tt] = pk;
            }
        } else {
            float bv = OUT_BIAS ? bias[col] : 0.f;
            #pragma unroll
            for (int i = 0; i < 4; ++i) {
                #pragma unroll
                for (int r = 0; r < 4; ++r) {
                    int row = m0 + wm * 64 + i * 16 + qd * 4 + r;
                    if (OUT_BIAS)
                        Cf[(size_t)row * LDC + col] = acc[i][t][r] + bv;
                    else
                        Cb[(size_t)row * LDC + col] = f2bf(acc[i][t][r]);
                }
            }
        }
    }
}

// ---------------------------------------------------------------------------
// MFMA differential flash attention (R6 inner structure, split pass-pairs).
// grid (48, 32): x = bh (fastest -> XCD-pinned KV: 48 % 8 == 0, each XCD
// serves 6 heads x 512 KB KV, L2-resident). y -> QT = 31 - y: one 32-row
// Q-tile per block, longest blocks dispatched first (LPT balance;
// 1536 blocks = 3072 waves ~ 3 waves/SIMD vs the 128-VGPR cap of 4).
// block 128 = 2 indep waves, each wave: 16 q-rows, BOTH matrices.
// K and V register-double-buffered one tile ahead; P round-trip through
// wave-private LDS as packed (P1|P2) dwords + v_perm unpack.
// ---------------------------------------------------------------------------
__global__ __launch_bounds__(128, 3) void diff_attn_mfma(
    const unsigned short* __restrict__ Y, const unsigned short* __restrict__ Vt,
    const float* __restrict__ lam_buf, unsigned short* __restrict__ attn)
{
    __shared__ unsigned int PL32[2][16 * PW_S];   // [wave][row][key] packed P1|P2
    int bh = blockIdx.x;                          // fastest dim -> XCD-pinned
    int b = bh / Hc, h = bh - b * Hc;
    int QT = 31 - (int)blockIdx.y;                // longest first
    int tid = threadIdx.x, lane = tid & 63, wv = tid >> 6;
    int cl = lane & 15, qd = lane >> 4;
    float lamv = lam_buf[h];
    size_t rowbase = (size_t)(b * Tc) * YLD;
    const int hq = h * HSc;
    unsigned int* Pw = PL32[wv];
    const unsigned short* VtB = Vt + ((size_t)bh << 17);   // bh*128*1024
    const f32x4 zero4 = {0.f, 0.f, 0.f, 0.f};

    bf16x8 ka[2][4], kb[2][4], va[8], vb2[8];

    auto loadK = [&](int kt, bf16x8 kf[2][4]) {
        #pragma unroll
        for (int c = 0; c < 2; ++c) {
            size_t koff = rowbase + (size_t)(kt * 32 + c * 16 + cl) * YLD;
            kf[c][0] = *(const bf16x8*)(Y + koff + K1OFF + hq + qd * 8);
            kf[c][1] = *(const bf16x8*)(Y + koff + K1OFF + hq + 32 + qd * 8);
            kf[c][2] = *(const bf16x8*)(Y + koff + K2OFF + hq + qd * 8);
            kf[c][3] = *(const bf16x8*)(Y + koff + K2OFF + hq + 32 + qd * 8);
        }
    };
    auto loadV = [&](int kt, bf16x8 vf[8]) {
        #pragma unroll
        for (int ec = 0; ec < 8; ++ec)
            vf[ec] = *(const bf16x8*)(VtB + (((ec * 16 + cl) << 10) + kt * 32 + qd * 8));
    };

    int qrow = QT * 32 + wv * 16;

    size_t qoff = rowbase + (size_t)(qrow + cl) * YLD;
    bf16x8 q1a = *(const bf16x8*)(Y + qoff + Q1OFF + hq + qd * 8);
    bf16x8 q1b = *(const bf16x8*)(Y + qoff + Q1OFF + hq + 32 + qd * 8);
    bf16x8 q2a = *(const bf16x8*)(Y + qoff + Q2OFF + hq + qd * 8);
    bf16x8 q2b = *(const bf16x8*)(Y + qoff + Q2OFF + hq + 32 + qd * 8);

    f32x4 O1[8], O2[8];
    #pragma unroll
    for (int ec = 0; ec < 8; ++ec) { O1[ec] = zero4; O2[ec] = zero4; }
    float l1[4] = {0.f, 0.f, 0.f, 0.f}, l2[4] = {0.f, 0.f, 0.f, 0.f};

    auto tile = [&](int kt, bf16x8 kf[2][4], bf16x8 vf[8], bool diag) {
        f32x4 S1[2], S2[2];
        #pragma unroll
        for (int c = 0; c < 2; ++c) { S1[c] = zero4; S2[c] = zero4; }
        #pragma unroll
        for (int c = 0; c < 2; ++c) {
            S1[c] = __builtin_amdgcn_mfma_f32_16x16x32_bf16(q1a, kf[c][0], S1[c], 0, 0, 0);
            S1[c] = __builtin_amdgcn_mfma_f32_16x16x32_bf16(q1b, kf[c][1], S1[c], 0, 0, 0);
            S2[c] = __builtin_amdgcn_mfma_f32_16x16x32_bf16(q2a, kf[c][2], S2[c], 0, 0, 0);
            S2[c] = __builtin_amdgcn_mfma_f32_16x16x32_bf16(q2b, kf[c][3], S2[c], 0, 0, 0);
        }
        if (diag) {
            #pragma unroll
            for (int c = 0; c < 2; ++c) {
                int key_local = c * 16 + cl;
                #pragma unroll
                for (int r = 0; r < 4; ++r) {
                    int row_local = wv * 16 + qd * 4 + r;
                    if (key_local > row_local) { S1[c][r] = -1e30f; S2[c][r] = -1e30f; }
                }
            }
        }
        // p = exp(s/8) = exp2(s * 0.125*log2e): one v_mul + one v_exp each
        #pragma unroll
        for (int r = 0; r < 4; ++r) {
            float p10 = exp2f(S1[0][r] * EXP2SCALE);
            float p11 = exp2f(S1[1][r] * EXP2SCALE);
            float p20 = exp2f(S2[0][r] * EXP2SCALE);
            float p21 = exp2f(S2[1][r] * EXP2SCALE);
            l1[r] += p10 + p11;
            l2[r] += p20 + p21;
            int row = (qd << 2) + r;
            Pw[row * PW_S + cl]      = pack2bf(p10, p20);   // key = cl
            Pw[row * PW_S + cl + 16] = pack2bf(p11, p21);   // key = cl+16
        }
        // read back as A-operand fragments: row = cl, keys qd*8..qd*8+7
        const unsigned int* rp = Pw + cl * PW_S + qd * 8;
        uint4 L0 = *(const uint4*)(rp);
        uint4 L1 = *(const uint4*)(rp + 4);
        uint4 u1, u2;
        u1.x = __builtin_amdgcn_perm(L0.y, L0.x, 0x05040100u);
        u1.y = __builtin_amdgcn_perm(L0.w, L0.z, 0x05040100u);
        u1.z = __builtin_amdgcn_perm(L1.y, L1.x, 0x05040100u);
        u1.w = __builtin_amdgcn_perm(L1.w, L1.z, 0x05040100u);
        u2.x = __builtin_amdgcn_perm(L0.y, L0.x, 0x07060302u);
        u2.y = __builtin_amdgcn_perm(L0.w, L0.z, 0x07060302u);
        u2.z = __builtin_amdgcn_perm(L1.y, L1.x, 0x07060302u);
        u2.w = __builtin_amdgcn_perm(L1.w, L1.z, 0x07060302u);
        bf16x8 pa1 = __builtin_bit_cast(bf16x8, u1);
        bf16x8 pa2 = __builtin_bit_cast(bf16x8, u2);
        #pragma unroll
        for (int ec = 0; ec < 8; ++ec) {
            O1[ec] = __builtin_amdgcn_mfma_f32_16x16x32_bf16(pa1, vf[ec], O1[ec], 0, 0, 0);
            O2[ec] = __builtin_amdgcn_mfma_f32_16x16x32_bf16(pa2, vf[ec], O2[ec], 0, 0, 0);
        }
    };

    loadK(0, ka); loadV(0, va);
    for (int kt = 0; kt <= QT; kt += 2) {
        if (kt + 1 <= QT) { loadK(kt + 1, kb); loadV(kt + 1, vb2); }
        tile(kt, ka, va, kt == QT);
        if (kt + 1 <= QT) {
            if (kt + 2 <= QT) { loadK(kt + 2, ka); loadV(kt + 2, va); }
            tile(kt + 1, kb, vb2, kt + 1 == QT);
        }
    }

    // reduce l across the 16 column-lanes
    float w1[4], w2[4];
    #pragma unroll
    for (int r = 0; r < 4; ++r) {
        float a = l1[r], c = l2[r];
        a += __shfl_xor(a, 1); a += __shfl_xor(a, 2);
        a += __shfl_xor(a, 4); a += __shfl_xor(a, 8);
        c += __shfl_xor(c, 1); c += __shfl_xor(c, 2);
        c += __shfl_xor(c, 4); c += __shfl_xor(c, 8);
        w1[r] = 1.0f / a;
        w2[r] = lamv / c;
    }
    #pragma unroll
    for (int ec = 0; ec < 8; ++ec) {
        #pragma unroll
        for (int r = 0; r < 4; ++r) {
            size_t row = (size_t)(b * Tc + qrow + qd * 4 + r);
            attn[row * HVD + h * VDc + ec * 16 + cl] =
                f2bf(O1[ec][r] * w1[r] - O2[ec][r] * w2[r]);
        }
    }
}

// ---------------------------------------------------------------------------
// Fused row-stats + LayerNorm*0.2, in-place on bf16 attn. 128 thr/row.
// ---------------------------------------------------------------------------
__global__ __launch_bounds__(128) void ln_inplace(
    unsigned short* __restrict__ attn,
    const float* __restrict__ gnw, const float* __restrict__ gnb)
{
    int row = blockIdx.x, tid = threadIdx.x;
    unsigned short* p = attn + (size_t)row * HVD;
    float v[12];
    float s = 0.f, sq = 0.f;
    #pragma unroll
    for (int j = 0; j < 3; ++j) {
        int g = tid + j * 128;
        ushort4 u = *(const ushort4*)(p + g * 4);
        float x0 = bf2f(u.x), x1 = bf2f(u.y), x2 = bf2f(u.z), x3 = bf2f(u.w);
        v[j * 4 + 0] = x0; v[j * 4 + 1] = x1; v[j * 4 + 2] = x2; v[j * 4 + 3] = x3;
        s += x0 + x1 + x2 + x3;
        sq = fmaf(x0, x0, sq); sq = fmaf(x1, x1, sq);
        sq = fmaf(x2, x2, sq); sq = fmaf(x3, x3, sq);
    }
    #pragma unroll
    for (int off = 32; off; off >>= 1) { s += __shfl_xor(s, off); sq += __shfl_xor(sq, off); }
    __shared__ float ss[2], sqs[2];
    if ((tid & 63) == 0) { ss[tid >> 6] = s; sqs[tid >> 6] = sq; }
    __syncthreads();
    float S = ss[0] + ss[1], Q = sqs[0] + sqs[1];
    float mu = S * (1.0f / HVD);
    float rstd = rsqrtf(Q * (1.0f / HVD) - mu * mu + 1e-5f);
    #pragma unroll
    for (int j = 0; j < 3; ++j) {
        int g = tid + j * 128;
        float4 gw = *(const float4*)(gnw + g * 4);
        float4 gb = *(const float4*)(gnb + g * 4);
        ushort4 o;
        o.x = f2bf(((v[j * 4 + 0] - mu) * rstd * gw.x + gb.x) * 0.2f);
        o.y = f2bf(((v[j * 4 + 1] - mu) * rstd * gw.y + gb.y) * 0.2f);
        o.z = f2bf(((v[j * 4 + 2] - mu) * rstd * gw.z + gb.z) * 0.2f);
        o.w = f2bf(((v[j * 4 + 3] - mu) * rstd * gw.w + gb.w) * 0.2f);
        *(ushort4*)(p + g * 4) = o;
    }
}

// ---------------------------------------------------------------------------
// launch
// ---------------------------------------------------------------------------
extern "C" void kernel_launch(void* const* d_in, const int* in_sizes, int n_in,
                              void* d_out, int out_size, void* d_ws, size_t ws_size,
                              hipStream_t stream)
{
    const float* x   = (const float*)d_in[0];
    const float* Wq1 = (const float*)d_in[1];
    const float* Wk1 = (const float*)d_in[2];
    const float* Wq2 = (const float*)d_in[3];
    const float* Wk2 = (const float*)d_in[4];
    const float* Wv  = (const float*)d_in[5];
    const float* lq1 = (const float*)d_in[6];
    const float* lk1 = (const float*)d_in[7];
    const float* lq2 = (const float*)d_in[8];
    const float* lk2 = (const float*)d_in[9];
    const float* gnw = (const float*)d_in[10];
    const float* gnb = (const float*)d_in[11];
    const float* Wp  = (const float*)d_in[12];
    const float* bp  = (const float*)d_in[13];
    const int*   lidx = (const int*)d_in[14];
    float* out = (float*)d_out;

    // workspace layout (bytes):
    // WcatT bf16 [4608][768]:  7,077,888 @ 0
    // Xb    bf16 [4096][768]:  6,291,456 @ 7,077,888
    // Y     bf16 [4096][3072]: 25,165,824 @ 13,369,344
    // Vt    bf16 [48][128][1024]: 12,582,912 @ 38,535,168
    // attn  bf16 [4096][1536]: 12,582,912 @ 51,118,080
    // Wpb   bf16 [768][1536]:   2,359,296 @ 63,700,992
    // lam   f32 [12]                       @ 66,060,288
    char* w = (char*)d_ws;
    unsigned short* WcatT = (unsigned short*)(w);
    unsigned short* Xb    = (unsigned short*)(w + 7077888);
    unsigned short* Y     = (unsigned short*)(w + 13369344);
    unsigned short* VtW   = (unsigned short*)(w + 38535168);
    unsigned short* attn  = (unsigned short*)(w + 51118080);
    unsigned short* Wpb   = (unsigned short*)(w + 63700992);
    float* lam            = (float*)(w + 66060288);

    cast_bf16<<<dim3(NROWS * Cc / 1024), 256, 0, stream>>>(x, Xb);
    cast_bf16<<<dim3(Cc * HVD / 1024), 256, 0, stream>>>(Wp, Wpb);
    trans_w<<<dim3(72 * 12), 256, 0, stream>>>(Wq1, Wk1, Wq2, Wk2, Wv, WcatT);
    lambda_kernel<<<dim3(Hc), 64, 0, stream>>>(lq1, lk1, lq2, lk2, lidx, lam);
    // QKV: [4096,768] x [768,4608]; Q/K -> Y (LD 3072), V -> Vt transposed
    gemm_mfma<4, 768, YLD, false, true><<<dim3(NQKV / 128, NROWS / 128), 256, 0, stream>>>(
        Xb, WcatT, Y, nullptr, nullptr, VtW);
    // bh fastest (XCD pin); y -> QT = 31-y, longest-first; 1536 blocks
    diff_attn_mfma<<<dim3(Bc * Hc, 32), 128, 0, stream>>>(Y, VtW, lam, attn);
    ln_inplace<<<dim3(NROWS), 128, 0, stream>>>(attn, gnw, gnb);
    // OUT: [4096,1536] x [1536,768] -> out fp32 (+bias)
    gemm_mfma<2, HVD, Cc, true, false><<<dim3(Cc / 64, NROWS / 128), 256, 0, stream>>>(
        attn, Wpb, nullptr, out, bp, nullptr);
}

// Round 9
// 292.916 us; speedup vs baseline: 1.4666x; 1.4666x over previous
//
#include <hip/hip_runtime.h>
#include <hip/hip_bf16.h>

// Problem constants
#define Bc   4
#define Tc   1024
#define Cc   768
#define Hc   12
#define HSc  64
#define VDc  128
#define NQKV 4608   // gemm N for qkv (4*768 Q/K + 1536 V)
#define YLD  3072   // Y row stride: Q/K only (V goes to Vt)
#define NROWS 4096  // B*T
#define HVD  1536   // H*VD

// Y (qk) column offsets
#define Q1OFF 0
#define K1OFF 768
#define Q2OFF 1536
#define K2OFF 2304

typedef __bf16 bf16x8 __attribute__((ext_vector_type(8)));
typedef float f32x4 __attribute__((ext_vector_type(4)));

#define PW_S 36   // P row stride in dwords: 144B rows, 16B aligned, <=2-way banks
// exp(s*0.125) == exp2(s * 0.125*log2(e))
#define EXP2SCALE 0.18033688011112042f

static __device__ __forceinline__ float bf2f(unsigned short s) {
    return __uint_as_float(((unsigned int)s) << 16);
}
static __device__ __forceinline__ unsigned short f2bf(float f) {
    unsigned int u = __float_as_uint(f);
    unsigned int r = (u + 0x7FFFu + ((u >> 16) & 1u)) >> 16;  // round-nearest-even
    return (unsigned short)r;
}
static __device__ __forceinline__ unsigned int pack2bf(float lo, float hi) {
    // bf16(lo) | bf16(hi)<<16, half-up rounding (values >= 0)
    unsigned int a = (__float_as_uint(lo) + 0x8000u) >> 16;
    unsigned int b = (__float_as_uint(hi) + 0x8000u) & 0xFFFF0000u;
    return a | b;
}

// async global->LDS 16B per lane; lds base must be wave-uniform
static __device__ __forceinline__ void load16_lds(const void* g, void* l) {
    __builtin_amdgcn_global_load_lds(
        (const __attribute__((address_space(1))) void*)g,
        (__attribute__((address_space(3))) void*)l, 16, 0, 0);
}

// ---------------------------------------------------------------------------
// cast fp32 -> bf16, 4 elts/thread
// ---------------------------------------------------------------------------
__global__ __launch_bounds__(256) void cast_bf16(
    const float* __restrict__ src, unsigned short* __restrict__ dst)
{
    int i = blockIdx.x * 256 + threadIdx.x;
    float4 v = *(const float4*)(src + (size_t)i * 4);
    ushort4 u;
    u.x = f2bf(v.x); u.y = f2bf(v.y); u.z = f2bf(v.z); u.w = f2bf(v.w);
    *(ushort4*)(dst + (size_t)i * 4) = u;
}

// ---------------------------------------------------------------------------
// Transpose-repack the 5 projection weights into WcatT[n][k] bf16, k-contig.
// ---------------------------------------------------------------------------
__global__ __launch_bounds__(256) void trans_w(
    const float* __restrict__ Wq1, const float* __restrict__ Wk1,
    const float* __restrict__ Wq2, const float* __restrict__ Wk2,
    const float* __restrict__ Wv, unsigned short* __restrict__ WcatT)
{
    __shared__ float tile[64][65];
    int tid = threadIdx.x;
    int t = blockIdx.x;
    int kt = t % 12, nt = t / 12;
    int k0 = kt * 64, n0 = nt * 64;
    const float* src;
    int stride;
    if (n0 < 3072) {
        int which = n0 / 768, m = n0 - which * 768, h = m >> 6;
        const float* W = (which == 0) ? Wq1 : (which == 1) ? Wk1 : (which == 2) ? Wq2 : Wk2;
        src = W + ((size_t)h * 768 + k0) * 64;
        stride = 64;
    } else {
        int rel = n0 - 3072, h = rel >> 7, e0 = rel & 127;
        src = Wv + ((size_t)h * 768 + k0) * 128 + e0;
        stride = 128;
    }
    for (int i = tid; i < 4096; i += 256) {
        int kl = i >> 6, dl = i & 63;
        tile[dl][kl] = src[(size_t)kl * stride + dl];
    }
    __syncthreads();
    for (int i = tid; i < 4096; i += 256) {
        int nl = i >> 6, kl = i & 63;
        WcatT[(size_t)(n0 + nl) * 768 + k0 + kl] = f2bf(tile[nl][kl]);
    }
}

// ---------------------------------------------------------------------------
// lambda per head
// ---------------------------------------------------------------------------
__global__ __launch_bounds__(64) void lambda_kernel(
    const float* __restrict__ lq1, const float* __restrict__ lk1,
    const float* __restrict__ lq2, const float* __restrict__ lk2,
    const int* __restrict__ layer_idx, float* __restrict__ lam)
{
    int h = blockIdx.x, l = threadIdx.x;
    float li = (float)layer_idx[0];
    float dyn = 0.8f - 0.6f * expf(-0.3f * (li - 1.0f));
    int i = h * HSc + l;
    float v = expf(lq1[i] * lk1[i]) - expf(lq2[i] * lk2[i]) + dyn;
    #pragma unroll
    for (int off = 32; off; off >>= 1) v += __shfl_xor(v, off);
    if (l == 0) lam[h] = v * (1.0f / 64.0f);
}

// ---------------------------------------------------------------------------
// MFMA GEMM (m97 structure): C[M][LDC] = A[M][KD] * Bt[N][KD]^T, bf16 inputs.
// SPLITV: cols >= 3072 (V projection) -> written transposed to VtOut[bh][e][t].
// ---------------------------------------------------------------------------
template<int TN, int KD, int LDC, bool OUT_BIAS, bool SPLITV>
__global__ __launch_bounds__(256) void gemm_mfma(
    const unsigned short* __restrict__ A, const unsigned short* __restrict__ Bt,
    unsigned short* __restrict__ Cb, float* __restrict__ Cf,
    const float* __restrict__ bias, unsigned short* __restrict__ VtOut)
{
    constexpr int BN = TN * 32;
    constexpr int JB = TN / 2;
    __shared__ unsigned short As[128 * 32];
    __shared__ unsigned short Bs[BN * 32];
    int tid = threadIdx.x, lane = tid & 63, w = tid >> 6;
    int wm = w >> 1, wn = w & 1;
    int m0 = blockIdx.y * 128, n0 = blockIdx.x * BN;

    int lr = lane >> 2, lq = lane & 3;
    const unsigned short* gA[2];
    const unsigned short* gB[JB];
    #pragma unroll
    for (int j = 0; j < 2; ++j) {
        int row = w * 32 + j * 16 + lr;
        int qg = lq ^ ((row >> 1) & 3);
        gA[j] = A + (size_t)(m0 + row) * KD + qg * 8;
    }
    #pragma unroll
    for (int j = 0; j < JB; ++j) {
        int row = w * (JB * 16) + j * 16 + lr;
        int qg = lq ^ ((row >> 1) & 3);
        gB[j] = Bt + (size_t)(n0 + row) * KD + qg * 8;
    }

    int rr = lane & 15, qd = lane >> 4;
    const unsigned short* aAddr[4];
    const unsigned short* bAddr[TN];
    #pragma unroll
    for (int i = 0; i < 4; ++i) {
        int row = wm * 64 + i * 16 + rr;
        int qs = qd ^ ((row >> 1) & 3);
        aAddr[i] = As + row * 32 + qs * 8;
    }
    #pragma unroll
    for (int t = 0; t < TN; ++t) {
        int row = wn * (TN * 16) + t * 16 + rr;
        int qs = qd ^ ((row >> 1) & 3);
        bAddr[t] = Bs + row * 32 + qs * 8;
    }

    f32x4 acc[4][TN];
    #pragma unroll
    for (int i = 0; i < 4; ++i)
        #pragma unroll
        for (int t = 0; t < TN; ++t) acc[i][t] = {0.f, 0.f, 0.f, 0.f};

    for (int k = 0; k < KD / 32; ++k) {
        __syncthreads();
        load16_lds(gA[0], As + (w * 2 + 0) * 512);
        load16_lds(gA[1], As + (w * 2 + 1) * 512);
        #pragma unroll
        for (int j = 0; j < JB; ++j)
            load16_lds(gB[j], Bs + (w * JB + j) * 512);
        gA[0] += 32; gA[1] += 32;
        #pragma unroll
        for (int j = 0; j < JB; ++j) gB[j] += 32;
        __syncthreads();

        bf16x8 af[4], bfr[TN];
        #pragma unroll
        for (int i = 0; i < 4; ++i) af[i] = *(const bf16x8*)aAddr[i];
        #pragma unroll
        for (int t = 0; t < TN; ++t) bfr[t] = *(const bf16x8*)bAddr[t];
        #pragma unroll
        for (int i = 0; i < 4; ++i)
            #pragma unroll
            for (int t = 0; t < TN; ++t)
                acc[i][t] = __builtin_amdgcn_mfma_f32_16x16x32_bf16(af[i], bfr[t], acc[i][t], 0, 0, 0);
    }

    #pragma unroll
    for (int t = 0; t < TN; ++t) {
        int col = n0 + wn * (TN * 16) + t * 16 + rr;
        if (SPLITV && col >= 3072) {
            int rel = col - 3072, hh = rel >> 7, e = rel & 127;
            #pragma unroll
            for (int i = 0; i < 4; ++i) {
                int row0 = m0 + wm * 64 + i * 16 + qd * 4;
                int b = row0 >> 10, tt = row0 & 1023;
                ushort4 pk;
                pk.x = f2bf(acc[i][t][0]); pk.y = f2bf(acc[i][t][1]);
                pk.z = f2bf(acc[i][t][2]); pk.w = f2bf(acc[i][t][3]);
                *(ushort4*)&VtOut[(size_t)((b * Hc + hh) * 128 + e) * 1024 + tt] = pk;
            }
        } else {
            float bv = OUT_BIAS ? bias[col] : 0.f;
            #pragma unroll
            for (int i = 0; i < 4; ++i) {
                #pragma unroll
                for (int r = 0; r < 4; ++r) {
                    int row = m0 + wm * 64 + i * 16 + qd * 4 + r;
                    if (OUT_BIAS)
                        Cf[(size_t)row * LDC + col] = acc[i][t][r] + bv;
                    else
                        Cb[(size_t)row * LDC + col] = f2bf(acc[i][t][r]);
                }
            }
        }
    }
}

// ---------------------------------------------------------------------------
// MFMA differential flash attention (R6 inner structure + register budget,
// R8 split-pass grid).
// grid (48, 32): x = bh (fastest -> XCD-pinned KV: 48 % 8 == 0, each XCD
// serves 6 heads x 512 KB KV, L2-resident). y -> QT = 31 - y: one 32-row
// Q-tile per block, longest blocks dispatched first (LPT balance).
// block 128 = 2 indep waves, each wave: 16 q-rows, BOTH matrices.
// __launch_bounds__(128, 2): VGPR budget 128 + AGPR accumulators, NO SPILL
// (R8's (128,3) squeezed to 84 VGPR -> 508 MB scratch spill traffic).
// K and V register-double-buffered one tile ahead; P round-trip through
// wave-private LDS as packed (P1|P2) dwords + v_perm unpack.
// ---------------------------------------------------------------------------
__global__ __launch_bounds__(128, 2) void diff_attn_mfma(
    const unsigned short* __restrict__ Y, const unsigned short* __restrict__ Vt,
    const float* __restrict__ lam_buf, unsigned short* __restrict__ attn)
{
    __shared__ unsigned int PL32[2][16 * PW_S];   // [wave][row][key] packed P1|P2
    int bh = blockIdx.x;                          // fastest dim -> XCD-pinned
    int b = bh / Hc, h = bh - b * Hc;
    int QT = 31 - (int)blockIdx.y;                // longest first
    int tid = threadIdx.x, lane = tid & 63, wv = tid >> 6;
    int cl = lane & 15, qd = lane >> 4;
    float lamv = lam_buf[h];
    size_t rowbase = (size_t)(b * Tc) * YLD;
    const int hq = h * HSc;
    unsigned int* Pw = PL32[wv];
    const unsigned short* VtB = Vt + ((size_t)bh << 17);   // bh*128*1024
    const f32x4 zero4 = {0.f, 0.f, 0.f, 0.f};

    bf16x8 ka[2][4], kb[2][4], va[8], vb2[8];

    auto loadK = [&](int kt, bf16x8 kf[2][4]) {
        #pragma unroll
        for (int c = 0; c < 2; ++c) {
            size_t koff = rowbase + (size_t)(kt * 32 + c * 16 + cl) * YLD;
            kf[c][0] = *(const bf16x8*)(Y + koff + K1OFF + hq + qd * 8);
            kf[c][1] = *(const bf16x8*)(Y + koff + K1OFF + hq + 32 + qd * 8);
            kf[c][2] = *(const bf16x8*)(Y + koff + K2OFF + hq + qd * 8);
            kf[c][3] = *(const bf16x8*)(Y + koff + K2OFF + hq + 32 + qd * 8);
        }
    };
    auto loadV = [&](int kt, bf16x8 vf[8]) {
        #pragma unroll
        for (int ec = 0; ec < 8; ++ec)
            vf[ec] = *(const bf16x8*)(VtB + (((ec * 16 + cl) << 10) + kt * 32 + qd * 8));
    };

    int qrow = QT * 32 + wv * 16;

    size_t qoff = rowbase + (size_t)(qrow + cl) * YLD;
    bf16x8 q1a = *(const bf16x8*)(Y + qoff + Q1OFF + hq + qd * 8);
    bf16x8 q1b = *(const bf16x8*)(Y + qoff + Q1OFF + hq + 32 + qd * 8);
    bf16x8 q2a = *(const bf16x8*)(Y + qoff + Q2OFF + hq + qd * 8);
    bf16x8 q2b = *(const bf16x8*)(Y + qoff + Q2OFF + hq + 32 + qd * 8);

    f32x4 O1[8], O2[8];
    #pragma unroll
    for (int ec = 0; ec < 8; ++ec) { O1[ec] = zero4; O2[ec] = zero4; }
    float l1[4] = {0.f, 0.f, 0.f, 0.f}, l2[4] = {0.f, 0.f, 0.f, 0.f};

    auto tile = [&](int kt, bf16x8 kf[2][4], bf16x8 vf[8], bool diag) {
        f32x4 S1[2], S2[2];
        #pragma unroll
        for (int c = 0; c < 2; ++c) { S1[c] = zero4; S2[c] = zero4; }
        #pragma unroll
        for (int c = 0; c < 2; ++c) {
            S1[c] = __builtin_amdgcn_mfma_f32_16x16x32_bf16(q1a, kf[c][0], S1[c], 0, 0, 0);
            S1[c] = __builtin_amdgcn_mfma_f32_16x16x32_bf16(q1b, kf[c][1], S1[c], 0, 0, 0);
            S2[c] = __builtin_amdgcn_mfma_f32_16x16x32_bf16(q2a, kf[c][2], S2[c], 0, 0, 0);
            S2[c] = __builtin_amdgcn_mfma_f32_16x16x32_bf16(q2b, kf[c][3], S2[c], 0, 0, 0);
        }
        if (diag) {
            #pragma unroll
            for (int c = 0; c < 2; ++c) {
                int key_local = c * 16 + cl;
                #pragma unroll
                for (int r = 0; r < 4; ++r) {
                    int row_local = wv * 16 + qd * 4 + r;
                    if (key_local > row_local) { S1[c][r] = -1e30f; S2[c][r] = -1e30f; }
                }
            }
        }
        // p = exp(s/8) = exp2(s * 0.125*log2e): one v_mul + one v_exp each
        #pragma unroll
        for (int r = 0; r < 4; ++r) {
            float p10 = exp2f(S1[0][r] * EXP2SCALE);
            float p11 = exp2f(S1[1][r] * EXP2SCALE);
            float p20 = exp2f(S2[0][r] * EXP2SCALE);
            float p21 = exp2f(S2[1][r] * EXP2SCALE);
            l1[r] += p10 + p11;
            l2[r] += p20 + p21;
            int row = (qd << 2) + r;
            Pw[row * PW_S + cl]      = pack2bf(p10, p20);   // key = cl
            Pw[row * PW_S + cl + 16] = pack2bf(p11, p21);   // key = cl+16
        }
        // read back as A-operand fragments: row = cl, keys qd*8..qd*8+7
        const unsigned int* rp = Pw + cl * PW_S + qd * 8;
        uint4 L0 = *(const uint4*)(rp);
        uint4 L1 = *(const uint4*)(rp + 4);
        uint4 u1, u2;
        u1.x = __builtin_amdgcn_perm(L0.y, L0.x, 0x05040100u);
        u1.y = __builtin_amdgcn_perm(L0.w, L0.z, 0x05040100u);
        u1.z = __builtin_amdgcn_perm(L1.y, L1.x, 0x05040100u);
        u1.w = __builtin_amdgcn_perm(L1.w, L1.z, 0x05040100u);
        u2.x = __builtin_amdgcn_perm(L0.y, L0.x, 0x07060302u);
        u2.y = __builtin_amdgcn_perm(L0.w, L0.z, 0x07060302u);
        u2.z = __builtin_amdgcn_perm(L1.y, L1.x, 0x07060302u);
        u2.w = __builtin_amdgcn_perm(L1.w, L1.z, 0x07060302u);
        bf16x8 pa1 = __builtin_bit_cast(bf16x8, u1);
        bf16x8 pa2 = __builtin_bit_cast(bf16x8, u2);
        #pragma unroll
        for (int ec = 0; ec < 8; ++ec) {
            O1[ec] = __builtin_amdgcn_mfma_f32_16x16x32_bf16(pa1, vf[ec], O1[ec], 0, 0, 0);
            O2[ec] = __builtin_amdgcn_mfma_f32_16x16x32_bf16(pa2, vf[ec], O2[ec], 0, 0, 0);
        }
    };

    loadK(0, ka); loadV(0, va);
    for (int kt = 0; kt <= QT; kt += 2) {
        if (kt + 1 <= QT) { loadK(kt + 1, kb); loadV(kt + 1, vb2); }
        tile(kt, ka, va, kt == QT);
        if (kt + 1 <= QT) {
            if (kt + 2 <= QT) { loadK(kt + 2, ka); loadV(kt + 2, va); }
            tile(kt + 1, kb, vb2, kt + 1 == QT);
        }
    }

    // reduce l across the 16 column-lanes
    float w1[4], w2[4];
    #pragma unroll
    for (int r = 0; r < 4; ++r) {
        float a = l1[r], c = l2[r];
        a += __shfl_xor(a, 1); a += __shfl_xor(a, 2);
        a += __shfl_xor(a, 4); a += __shfl_xor(a, 8);
        c += __shfl_xor(c, 1); c += __shfl_xor(c, 2);
        c += __shfl_xor(c, 4); c += __shfl_xor(c, 8);
        w1[r] = 1.0f / a;
        w2[r] = lamv / c;
    }
    #pragma unroll
    for (int ec = 0; ec < 8; ++ec) {
        #pragma unroll
        for (int r = 0; r < 4; ++r) {
            size_t row = (size_t)(b * Tc + qrow + qd * 4 + r);
            attn[row * HVD + h * VDc + ec * 16 + cl] =
                f2bf(O1[ec][r] * w1[r] - O2[ec][r] * w2[r]);
        }
    }
}

// ---------------------------------------------------------------------------
// Fused row-stats + LayerNorm*0.2, in-place on bf16 attn. 128 thr/row.
// ---------------------------------------------------------------------------
__global__ __launch_bounds__(128) void ln_inplace(
    unsigned short* __restrict__ attn,
    const float* __restrict__ gnw, const float* __restrict__ gnb)
{
    int row = blockIdx.x, tid = threadIdx.x;
    unsigned short* p = attn + (size_t)row * HVD;
    float v[12];
    float s = 0.f, sq = 0.f;
    #pragma unroll
    for (int j = 0; j < 3; ++j) {
        int g = tid + j * 128;
        ushort4 u = *(const ushort4*)(p + g * 4);
        float x0 = bf2f(u.x), x1 = bf2f(u.y), x2 = bf2f(u.z), x3 = bf2f(u.w);
        v[j * 4 + 0] = x0; v[j * 4 + 1] = x1; v[j * 4 + 2] = x2; v[j * 4 + 3] = x3;
        s += x0 + x1 + x2 + x3;
        sq = fmaf(x0, x0, sq); sq = fmaf(x1, x1, sq);
        sq = fmaf(x2, x2, sq); sq = fmaf(x3, x3, sq);
    }
    #pragma unroll
    for (int off = 32; off; off >>= 1) { s += __shfl_xor(s, off); sq += __shfl_xor(sq, off); }
    __shared__ float ss[2], sqs[2];
    if ((tid & 63) == 0) { ss[tid >> 6] = s; sqs[tid >> 6] = sq; }
    __syncthreads();
    float S = ss[0] + ss[1], Q = sqs[0] + sqs[1];
    float mu = S * (1.0f / HVD);
    float rstd = rsqrtf(Q * (1.0f / HVD) - mu * mu + 1e-5f);
    #pragma unroll
    for (int j = 0; j < 3; ++j) {
        int g = tid + j * 128;
        float4 gw = *(const float4*)(gnw + g * 4);
        float4 gb = *(const float4*)(gnb + g * 4);
        ushort4 o;
        o.x = f2bf(((v[j * 4 + 0] - mu) * rstd * gw.x + gb.x) * 0.2f);
        o.y = f2bf(((v[j * 4 + 1] - mu) * rstd * gw.y + gb.y) * 0.2f);
        o.z = f2bf(((v[j * 4 + 2] - mu) * rstd * gw.z + gb.z) * 0.2f);
        o.w = f2bf(((v[j * 4 + 3] - mu) * rstd * gw.w + gb.w) * 0.2f);
        *(ushort4*)(p + g * 4) = o;
    }
}

// ---------------------------------------------------------------------------
// launch
// ---------------------------------------------------------------------------
extern "C" void kernel_launch(void* const* d_in, const int* in_sizes, int n_in,
                              void* d_out, int out_size, void* d_ws, size_t ws_size,
                              hipStream_t stream)
{
    const float* x   = (const float*)d_in[0];
    const float* Wq1 = (const float*)d_in[1];
    const float* Wk1 = (const float*)d_in[2];
    const float* Wq2 = (const float*)d_in[3];
    const float* Wk2 = (const float*)d_in[4];
    const float* Wv  = (const float*)d_in[5];
    const float* lq1 = (const float*)d_in[6];
    const float* lk1 = (const float*)d_in[7];
    const float* lq2 = (const float*)d_in[8];
    const float* lk2 = (const float*)d_in[9];
    const float* gnw = (const float*)d_in[10];
    const float* gnb = (const float*)d_in[11];
    const float* Wp  = (const float*)d_in[12];
    const float* bp  = (const float*)d_in[13];
    const int*   lidx = (const int*)d_in[14];
    float* out = (float*)d_out;

    // workspace layout (bytes):
    // WcatT bf16 [4608][768]:  7,077,888 @ 0
    // Xb    bf16 [4096][768]:  6,291,456 @ 7,077,888
    // Y     bf16 [4096][3072]: 25,165,824 @ 13,369,344
    // Vt    bf16 [48][128][1024]: 12,582,912 @ 38,535,168
    // attn  bf16 [4096][1536]: 12,582,912 @ 51,118,080
    // Wpb   bf16 [768][1536]:   2,359,296 @ 63,700,992
    // lam   f32 [12]                       @ 66,060,288
    char* w = (char*)d_ws;
    unsigned short* WcatT = (unsigned short*)(w);
    unsigned short* Xb    = (unsigned short*)(w + 7077888);
    unsigned short* Y     = (unsigned short*)(w + 13369344);
    unsigned short* VtW   = (unsigned short*)(w + 38535168);
    unsigned short* attn  = (unsigned short*)(w + 51118080);
    unsigned short* Wpb   = (unsigned short*)(w + 63700992);
    float* lam            = (float*)(w + 66060288);

    cast_bf16<<<dim3(NROWS * Cc / 1024), 256, 0, stream>>>(x, Xb);
    cast_bf16<<<dim3(Cc * HVD / 1024), 256, 0, stream>>>(Wp, Wpb);
    trans_w<<<dim3(72 * 12), 256, 0, stream>>>(Wq1, Wk1, Wq2, Wk2, Wv, WcatT);
    lambda_kernel<<<dim3(Hc), 64, 0, stream>>>(lq1, lk1, lq2, lk2, lidx, lam);
    // QKV: [4096,768] x [768,4608]; Q/K -> Y (LD 3072), V -> Vt transposed
    gemm_mfma<4, 768, YLD, false, true><<<dim3(NQKV / 128, NROWS / 128), 256, 0, stream>>>(
        Xb, WcatT, Y, nullptr, nullptr, VtW);
    // bh fastest (XCD pin); y -> QT = 31-y, longest-first; 1536 blocks
    diff_attn_mfma<<<dim3(Bc * Hc, 32), 128, 0, stream>>>(Y, VtW, lam, attn);
    ln_inplace<<<dim3(NROWS), 128, 0, stream>>>(attn, gnw, gnb);
    // OUT: [4096,1536] x [1536,768] -> out fp32 (+bias)
    gemm_mfma<2, HVD, Cc, true, false><<<dim3(Cc / 64, NROWS / 128), 256, 0, stream>>>(
        attn, Wpb, nullptr, out, bp, nullptr);
}